// Round 2
// baseline (501.843 us; speedup 1.0000x reference)
//
#include <hip/hip_runtime.h>

// Matrix-factorization forward:
//   pred[b] = sum_h (uw[u][h] + ub[u]) * (iw[i][h] + ib[i]) + bias[0]
// B = 1,048,576, H = 64.
//
// Layout: 16 lanes per row -> one contiguous 256 B float4 read per table per
// row (perfect coalescing). Each thread processes TWO independent rows
// (rowA, rowB = rowA+16) so each wave keeps 16 x 256 B gathers in flight
// instead of 8 -> hides the dependent idx->weight load chain.

__global__ __launch_bounds__(256) void MF_73856257622285_kernel(
    const int*   __restrict__ user,
    const int*   __restrict__ item,
    const float* __restrict__ user_weight,
    const float* __restrict__ item_weight,
    const float* __restrict__ user_bias,
    const float* __restrict__ item_bias,
    const float* __restrict__ bias,
    float*       __restrict__ out,
    int batch)
{
    const int lane16 = threadIdx.x & 15;
    const int grp    = threadIdx.x >> 4;          // 0..15
    const int rowA   = blockIdx.x * 32 + grp;
    const int rowB   = rowA + 16;

    const bool okA = rowA < batch;
    const bool okB = rowB < batch;

    // Issue both index pairs first (independent loads).
    const int uA = okA ? user[rowA] : 0;
    const int iA = okA ? item[rowA] : 0;
    const int uB = okB ? user[rowB] : 0;
    const int iB = okB ? item[rowB] : 0;

    // Four independent 256 B row gathers in flight per group.
    const float4 uwA = ((const float4*)(user_weight + (size_t)uA * 64))[lane16];
    const float4 iwA = ((const float4*)(item_weight + (size_t)iA * 64))[lane16];
    const float4 uwB = ((const float4*)(user_weight + (size_t)uB * 64))[lane16];
    const float4 iwB = ((const float4*)(item_weight + (size_t)iB * 64))[lane16];

    const float ubA = user_bias[uA];
    const float ibA = item_bias[iA];
    const float ubB = user_bias[uB];
    const float ibB = item_bias[iB];

    const float b0 = bias[0];

    float sA = (uwA.x + ubA) * (iwA.x + ibA)
             + (uwA.y + ubA) * (iwA.y + ibA)
             + (uwA.z + ubA) * (iwA.z + ibA)
             + (uwA.w + ubA) * (iwA.w + ibA);

    float sB = (uwB.x + ubB) * (iwB.x + ibB)
             + (uwB.y + ubB) * (iwB.y + ibB)
             + (uwB.z + ubB) * (iwB.z + ibB)
             + (uwB.w + ubB) * (iwB.w + ibB);

    // Reduce across the 16 lanes of this group (in-wave, no LDS).
    #pragma unroll
    for (int off = 8; off >= 1; off >>= 1) {
        sA += __shfl_xor(sA, off, 16);
        sB += __shfl_xor(sB, off, 16);
    }

    if (lane16 == 0) {
        if (okA) __builtin_nontemporal_store(sA + b0, &out[rowA]);
        if (okB) __builtin_nontemporal_store(sB + b0, &out[rowB]);
    }
}

extern "C" void kernel_launch(void* const* d_in, const int* in_sizes, int n_in,
                              void* d_out, int out_size, void* d_ws, size_t ws_size,
                              hipStream_t stream) {
    const int*   user        = (const int*)  d_in[0];
    const int*   item        = (const int*)  d_in[1];
    // d_in[2] = target (unused in forward)
    const float* user_weight = (const float*)d_in[3];
    const float* item_weight = (const float*)d_in[4];
    const float* user_bias   = (const float*)d_in[5];
    const float* item_bias   = (const float*)d_in[6];
    const float* bias        = (const float*)d_in[7];
    float*       out         = (float*)d_out;

    const int batch = in_sizes[0];

    const int threads = 256;
    const int rows_per_block = 32;                 // 2 rows per thread-group
    const int blocks = (batch + rows_per_block - 1) / rows_per_block;

    MF_73856257622285_kernel<<<blocks, threads, 0, stream>>>(
        user, item, user_weight, item_weight, user_bias, item_bias, bias,
        out, batch);
}

// Round 3
// 501.234 us; speedup vs baseline: 1.0012x; 1.0012x over previous
//
#include <hip/hip_runtime.h>

// Matrix-factorization forward:
//   pred[b] = sum_h (uw[u][h] + ub[u]) * (iw[i][h] + ib[i]) + bias[0]
// B = 1,048,576, H = 64.
//
// Layout: 16 lanes per row -> one contiguous 256 B float4 read per table per
// row (perfect coalescing). Each thread processes FOUR rows (base + k*16),
// all 8 index loads issued first, then all 8 row gathers -> 32 outstanding
// 256 B gathers per wave. Decisive MLP test vs. the random-gather BW floor.

__global__ __launch_bounds__(256) void MF_73856257622285_kernel(
    const int*   __restrict__ user,
    const int*   __restrict__ item,
    const float* __restrict__ user_weight,
    const float* __restrict__ item_weight,
    const float* __restrict__ user_bias,
    const float* __restrict__ item_bias,
    const float* __restrict__ bias,
    float*       __restrict__ out,
    int batch)
{
    const int lane16 = threadIdx.x & 15;
    const int grp    = threadIdx.x >> 4;          // 0..15
    const int row0   = blockIdx.x * 64 + grp;     // rows: row0 + {0,16,32,48}

    int u[4], it[4];
    bool ok[4];
    #pragma unroll
    for (int k = 0; k < 4; ++k) {
        const int r = row0 + k * 16;
        ok[k] = r < batch;
        u[k]  = ok[k] ? user[r] : 0;
        it[k] = ok[k] ? item[r] : 0;
    }

    // 8 independent 256 B row gathers in flight per thread.
    float4 uw[4], iw[4];
    #pragma unroll
    for (int k = 0; k < 4; ++k) {
        uw[k] = ((const float4*)(user_weight + (size_t)u[k]  * 64))[lane16];
        iw[k] = ((const float4*)(item_weight + (size_t)it[k] * 64))[lane16];
    }

    float ub[4], ib[4];
    #pragma unroll
    for (int k = 0; k < 4; ++k) {
        ub[k] = user_bias[u[k]];
        ib[k] = item_bias[it[k]];
    }

    const float b0 = bias[0];

    float s[4];
    #pragma unroll
    for (int k = 0; k < 4; ++k) {
        s[k] = (uw[k].x + ub[k]) * (iw[k].x + ib[k])
             + (uw[k].y + ub[k]) * (iw[k].y + ib[k])
             + (uw[k].z + ub[k]) * (iw[k].z + ib[k])
             + (uw[k].w + ub[k]) * (iw[k].w + ib[k]);
    }

    // Reduce across the 16 lanes of each group (in-wave, no LDS).
    #pragma unroll
    for (int off = 8; off >= 1; off >>= 1) {
        #pragma unroll
        for (int k = 0; k < 4; ++k) s[k] += __shfl_xor(s[k], off, 16);
    }

    if (lane16 == 0) {
        #pragma unroll
        for (int k = 0; k < 4; ++k) {
            if (ok[k]) __builtin_nontemporal_store(s[k] + b0, &out[row0 + k * 16]);
        }
    }
}

extern "C" void kernel_launch(void* const* d_in, const int* in_sizes, int n_in,
                              void* d_out, int out_size, void* d_ws, size_t ws_size,
                              hipStream_t stream) {
    const int*   user        = (const int*)  d_in[0];
    const int*   item        = (const int*)  d_in[1];
    // d_in[2] = target (unused in forward)
    const float* user_weight = (const float*)d_in[3];
    const float* item_weight = (const float*)d_in[4];
    const float* user_bias   = (const float*)d_in[5];
    const float* item_bias   = (const float*)d_in[6];
    const float* bias        = (const float*)d_in[7];
    float*       out         = (float*)d_out;

    const int batch = in_sizes[0];

    const int threads = 256;
    const int rows_per_block = 64;                 // 4 rows per thread-group
    const int blocks = (batch + rows_per_block - 1) / rows_per_block;

    MF_73856257622285_kernel<<<blocks, threads, 0, stream>>>(
        user, item, user_weight, item_weight, user_bias, item_bias, bias,
        out, batch);
}